// Round 3
// baseline (1645.920 us; speedup 1.0000x reference)
//
#include <hip/hip_runtime.h>
#include <hip/hip_bf16.h>

// LSNN forward: encoder(IF, soft reset) -> hidden(LIF alpha=0.9) -> leaky integrator out.
// Pipeline:
//   k_enc       : x -> s_e spike bitmasks [B][T][4]u64           (bit-exact vs ref)
//   k_quant     : W_hdn -> dual-plane bf16, MFMA-fragment-order layout (1 wave-load = 1KB)
//   k_quant_o   : W_otp -> dual-plane bf16 [n=16 pad][k=2048]
//   k_gemm_scan : SINGLE launch. Per wave: batch b x 128 n, loops 16 time-chunks.
//                 B-frags via direct global b128 loads (L2-hot), A-frags via LDS LUT,
//                 v_h in registers, ZERO barriers in the chunk/K loop.
//   k_outcur_mfma: s_h masks @ W_otp via MFMA -> I[b][t][c]
//   k_integ1/2/3: chunked parallel beta-scan of I -> d_out
//
// R3: merged 16 gemm launches -> 1 (v_h reg-resident); B staging LDS->global frag
//     loads (kills the 2-barriers-per-kt drain, the m97-class stall); epilogue
//     dual-chain interleave + b128 swizzled scratch.

#define BB 512
#define TT 1024
#define OO 128
#define KK 256
#define HH 1024
#define CC 10
#define TC 64
#define NCHUNK (TT / TC)

typedef unsigned long long u64;
typedef __attribute__((ext_vector_type(8))) short short8;   // 8 x bf16
typedef __attribute__((ext_vector_type(4))) float floatx4;
typedef __attribute__((ext_vector_type(4))) int intx4;

__device__ __forceinline__ unsigned short f2bf_rn(float f) {
    unsigned u = __float_as_uint(f);
    u += 0x7FFFu + ((u >> 16) & 1u);      // round-to-nearest-even (finite inputs)
    return (unsigned short)(u >> 16);
}
__device__ __forceinline__ float bf2f(unsigned short h) {
    return __uint_as_float(((unsigned)h) << 16);
}

// ---------------------------------------------------------------- encoder ----
__global__ __launch_bounds__(128) void k_enc(const float* __restrict__ x,
                                             u64* __restrict__ me) {
    const int b    = blockIdx.x;
    const int j    = threadIdx.x;       // channel 0..127
    const int wv   = j >> 6;            // wave 0/1
    const int lane = j & 63;
    const float* xb = x + (size_t)b * (TT * OO);
    float vp = 0.f, vn = 0.f;
    for (int t0 = 0; t0 < TT; t0 += 16) {
        float xs[16];
#pragma unroll
        for (int g = 0; g < 16; ++g) xs[g] = xb[(t0 + g) * OO + j];  // independent loads
#pragma unroll
        for (int g = 0; g < 16; ++g) {
            float xv = xs[g];
            float cp = fmaxf(xv, 0.f);
            float cn = fmaxf(-xv, 0.f);
            vp += cp;                    // same per-channel op order as ref -> bit-exact
            vn += cn;
            bool sp = (vp >= 1.0f);
            bool sn = (vn >= 1.0f);
            u64 mp = __ballot(sp);
            u64 mn = __ballot(sn);
            if (sp) vp -= 1.0f;
            if (sn) vn -= 1.0f;
            if (lane == 0) {
                size_t r = ((size_t)b * TT + (t0 + g)) * 4;
                me[r + wv]     = mp;
                me[r + 2 + wv] = mn;
            }
        }
    }
}

// ------------------------------ W_hdn dual-plane bf16, fragment-order layout --
// Source k: kt=k>>6, kw=(k>>5)&1, q=(k>>3)&3, e=k&7; plane lo for k>=256.
// 16B chunk index C = (kt*2+kw)*4096 + n*4 + q; element = C*8 + e.
// A wave's bfrag(kt,kw,ng) then reads 1 KB contiguous (lanes: l15*4+quad chunks).
__global__ __launch_bounds__(256) void k_quant(const float* __restrict__ Wh,
                                               unsigned short* __restrict__ Wt2) {
    int idx = blockIdx.x * 256 + threadIdx.x;   // 1024*512 total
    int n = idx >> 9;
    int k = idx & 511;
    float w = Wh[(size_t)(k & 255) * HH + n];
    unsigned short hi = f2bf_rn(w);
    unsigned short out = (k < KK) ? hi : f2bf_rn(w - bf2f(hi));
    int kt = k >> 6, kw = (k >> 5) & 1, q = (k >> 3) & 3, e = k & 7;
    size_t C = (size_t)(kt * 2 + kw) * 4096 + n * 4 + q;
    Wt2[C * 8 + e] = out;
}

// ---------------------------------------------------- W_otp dual-plane bf16 --
__global__ __launch_bounds__(256) void k_quant_o(const float* __restrict__ Wo,
                                                 unsigned short* __restrict__ Wqo) {
    int idx = blockIdx.x * 256 + threadIdx.x;   // 16*2048 = 32768
    int n = idx >> 11;
    int k = idx & 2047;
    unsigned short out = 0;
    if (n < CC) {
        float w = Wo[(size_t)(k & 1023) * CC + n];
        unsigned short hi = f2bf_rn(w);
        out = (k < HH) ? hi : f2bf_rn(w - bf2f(hi));
    }
    Wqo[(size_t)n * 2048 + k] = out;
}

// ------------------------------------------- fused GEMM + hidden LIF scan ----
// grid (128 mtiles, 8 ny), 256 threads. Wave = batch b = mtile*4+wave, n-slice
// ny*128..+128, loops all 16 chunks with v_h in registers. No barriers after LUT.
__global__ __launch_bounds__(256, 2) void k_gemm_scan(
    const u64* __restrict__ me, const unsigned short* __restrict__ Wt2,
    u64* __restrict__ mh) {
    __shared__ __align__(16) char smem[4096 + 4 * 8192];
    char*  Lut    = smem;                       // 4 KB: byte -> 8 x bf16 {0,1}
    float* ScrAll = (float*)(smem + 4096);      // 8 KB per wave epilogue scratch

    const int tid  = threadIdx.x;
    const int wave = tid >> 6;
    const int lane = tid & 63;
    const int quad = lane >> 4;
    const int l15  = lane & 15;
    const int mtile = blockIdx.x;               // 0..127
    const int ny    = blockIdx.y;               // 0..7
    const int b     = mtile * 4 + wave;         // this wave's batch
    float* scr = ScrAll + wave * 2048;          // 128 n x 16 t floats

    {   // build LUT (the only barrier in the kernel)
        unsigned e = (unsigned)tid;
        unsigned p0 = ((e >> 0) & 1) * 0x3F80u | ((e >> 1) & 1) * 0x3F800000u;
        unsigned p1 = ((e >> 2) & 1) * 0x3F80u | ((e >> 3) & 1) * 0x3F800000u;
        unsigned p2 = ((e >> 4) & 1) * 0x3F80u | ((e >> 5) & 1) * 0x3F800000u;
        unsigned p3 = ((e >> 6) & 1) * 0x3F80u | ((e >> 7) & 1) * 0x3F800000u;
        ((intx4*)Lut)[tid] = intx4{(int)p0, (int)p1, (int)p2, (int)p3};
    }
    __syncthreads();

    const short8* Bp = (const short8*)Wt2;
    const int swz = (l15 + (l15 >> 2)) & 3;     // scr swizzle, n-dependent part
    float va = 0.f, vb = 0.f;                   // v_h for n = ny*128+lane / +64+lane

#pragma unroll 1
    for (int ct = 0; ct < NCHUNK; ++ct) {
        const int t0 = ct * TC;

        floatx4 acc[4][8];
#pragma unroll
        for (int i = 0; i < 4; ++i)
#pragma unroll
            for (int j2 = 0; j2 < 8; ++j2) acc[i][j2] = floatx4{0.f, 0.f, 0.f, 0.f};

#pragma unroll 1
        for (int kt = 0; kt < 8; ++kt) {        // K = 8 * 64 (hi kt 0..3, lo 4..7)
            u64 aw[4];
#pragma unroll
            for (int mg = 0; mg < 4; ++mg)      // broadcast 8B loads, L1-hot
                aw[mg] = me[((size_t)b * TT + (t0 + mg * 16 + l15)) * 4 + (kt & 3)];
#pragma unroll
            for (int kw = 0; kw < 2; ++kw) {
                const int shift = kw * 32 + quad * 8;
                short8 afrag[4];
#pragma unroll
                for (int mg = 0; mg < 4; ++mg) {
                    unsigned byte = (unsigned)((aw[mg] >> shift) & 0xFFu);
                    afrag[mg] = *((const short8*)(Lut + byte * 16));
                }
                const size_t cbase = (size_t)(kt * 2 + kw) * 4096 + ny * 512
                                   + l15 * 4 + quad;
#pragma unroll
                for (int ng = 0; ng < 8; ++ng) {
                    short8 bfrag = Bp[cbase + ng * 64];   // 1KB contiguous wave-load
#pragma unroll
                    for (int mg = 0; mg < 4; ++mg)
                        acc[mg][ng] = __builtin_amdgcn_mfma_f32_16x16x32_bf16(
                            afrag[mg], bfrag, acc[mg][ng], 0, 0, 0);
                }
            }
        }

        // epilogue: LIF scan, 16 t per round, both 64-n halves interleaved.
        // scr layout: n-col major, float addr = n*16 + ((t4 ^ s(n))*4 + (t&3)).
#pragma unroll 1
        for (int mg = 0; mg < 4; ++mg) {
#pragma unroll
            for (int ng = 0; ng < 8; ++ng)      // rows quad*4+r, col ng*16+l15
                *((floatx4*)(scr + (ng * 16 + l15) * 16 + ((quad ^ swz) << 2))) =
                    acc[mg][ng];
            // per-wave scratch: compiler inserts lgkmcnt waits, no barrier needed
#pragma unroll
            for (int tt = 0; tt < 4; ++tt) {
                const int rsw = ((tt ^ swz) << 2);
                floatx4 ca = *((const floatx4*)(scr + lane * 16 + rsw));
                floatx4 cb = *((const floatx4*)(scr + (lane + 64) * 16 + rsw));
#pragma unroll
                for (int r = 0; r < 4; ++r) {
                    const int t = t0 + mg * 16 + tt * 4 + r;
                    va = fmaf(0.9f, va, ca[r]);
                    vb = fmaf(0.9f, vb, cb[r]);
                    bool sa = (va >= 1.0f);
                    bool sb = (vb >= 1.0f);
                    u64 ma = __ballot(sa);
                    u64 mb = __ballot(sb);
                    if (sa) va -= 1.0f;
                    if (sb) vb -= 1.0f;
                    if (lane == 0) {
                        u64* mp = mh + ((size_t)b * TT + t) * 16 + ny * 2;
                        mp[0] = ma;
                        mp[1] = mb;
                    }
                }
            }
        }
    }
}

// ------------------------------------- s_h masks @ W_otp via MFMA -> I -------
__global__ __launch_bounds__(256, 2) void k_outcur_mfma(
    const u64* __restrict__ mh, const unsigned short* __restrict__ Wqo,
    float* __restrict__ I) {
    __shared__ __align__(16) char smem[69632];
    char* Bo  = smem;                       // 64 KB: [n=16][k=2048] bf16, swizzled
    char* Lut = smem + 65536;               // 4 KB

    const int tid  = threadIdx.x;
    const int wave = tid >> 6;
    const int lane = tid & 63;
    const int quad = lane >> 4;
    const int l15  = lane & 15;

    {
#pragma unroll
        for (int i = 0; i < 16; ++i) {
            int pid = i * 256 + tid;        // 4096 pieces of 16 B
            int n = pid >> 8, p = pid & 255;
            intx4 v = ((const intx4*)Wqo)[pid];
            *((intx4*)(Bo + n * 4096 + ((p ^ (n & 7)) * 16))) = v;
        }
        unsigned e = (unsigned)tid;
        unsigned p0 = ((e >> 0) & 1) * 0x3F80u | ((e >> 1) & 1) * 0x3F800000u;
        unsigned p1 = ((e >> 2) & 1) * 0x3F80u | ((e >> 3) & 1) * 0x3F800000u;
        unsigned p2 = ((e >> 4) & 1) * 0x3F80u | ((e >> 5) & 1) * 0x3F800000u;
        unsigned p3 = ((e >> 6) & 1) * 0x3F80u | ((e >> 7) & 1) * 0x3F800000u;
        ((intx4*)(Lut))[tid] = intx4{(int)p0, (int)p1, (int)p2, (int)p3};
    }
    __syncthreads();

    const int tbase = blockIdx.x * 16 + wave * 4;   // 4 consecutive m-tiles per wave
    floatx4 acc[4];
#pragma unroll
    for (int tt = 0; tt < 4; ++tt) acc[tt] = floatx4{0.f, 0.f, 0.f, 0.f};

    const u64* rowp[4];
#pragma unroll
    for (int tt = 0; tt < 4; ++tt)
        rowp[tt] = mh + ((size_t)(tbase + tt) * 16 + l15) * 16;   // row m = tile*16+l15

    for (int wi = 0; wi < 16; ++wi) {
        u64 w[4];
#pragma unroll
        for (int tt = 0; tt < 4; ++tt) w[tt] = rowp[tt][wi];
#pragma unroll
        for (int half = 0; half < 2; ++half) {
            int shift = half * 32 + quad * 8;
            int kt_hi = 2 * wi + half;           // hi-plane K chunk
            int kt_lo = 32 + kt_hi;              // lo-plane (residual) K chunk
            int j_hi = kt_hi * 4 + quad;
            int j_lo = kt_lo * 4 + quad;
            short8 bhi = *((const short8*)(Bo + l15 * 4096 + ((j_hi ^ (l15 & 7)) * 16)));
            short8 blo = *((const short8*)(Bo + l15 * 4096 + ((j_lo ^ (l15 & 7)) * 16)));
#pragma unroll
            for (int tt = 0; tt < 4; ++tt) {
                unsigned byte = (unsigned)((w[tt] >> shift) & 0xFFu);
                short8 af = *((const short8*)(Lut + byte * 16));
                acc[tt] = __builtin_amdgcn_mfma_f32_16x16x32_bf16(af, bhi, acc[tt], 0, 0, 0);
                acc[tt] = __builtin_amdgcn_mfma_f32_16x16x32_bf16(af, blo, acc[tt], 0, 0, 0);
            }
        }
    }

#pragma unroll
    for (int tt = 0; tt < 4; ++tt)
#pragma unroll
        for (int r = 0; r < 4; ++r) {
            int m = (tbase + tt) * 16 + quad * 4 + r;
            if (l15 < CC) I[(size_t)m * CC + l15] = acc[tt][r];
        }
}

// -------------------------------------------- chunked leaky-integrator scan --
__global__ __launch_bounds__(192) void k_integ1(const float* __restrict__ I,
                                                float* __restrict__ out,
                                                float* __restrict__ vend) {
    int b = blockIdx.x;
    int tid = threadIdx.x;
    if (tid >= 160) return;
    int chunk = tid / 10, c = tid % 10;
    int t0 = chunk * 64;
    const float* Ib = I + ((size_t)b * TT + t0) * CC + c;
    float* ob = out + ((size_t)b * TT + t0) * CC + c;
    float v = 0.f;
    for (int g0 = 0; g0 < 64; g0 += 8) {
        float xs[8];
#pragma unroll
        for (int g = 0; g < 8; ++g) xs[g] = Ib[(g0 + g) * CC];
#pragma unroll
        for (int g = 0; g < 8; ++g) {
            v = 0.9f * v + xs[g];
            ob[(g0 + g) * CC] = v;
        }
    }
    vend[((size_t)b * 16 + chunk) * CC + c] = v;
}

__global__ __launch_bounds__(256) void k_integ2(const float* __restrict__ vend,
                                                float* __restrict__ carry) {
    int id = blockIdx.x * 256 + threadIdx.x;
    if (id >= BB * CC) return;
    int b = id / CC, c = id % CC;
    float d64 = 1.f;
#pragma unroll
    for (int i = 0; i < 64; ++i) d64 *= 0.9f;
    float cv = 0.f;
    for (int k = 0; k < 16; ++k) {
        carry[((size_t)b * 16 + k) * CC + c] = cv;
        cv = vend[((size_t)b * 16 + k) * CC + c] + d64 * cv;
    }
}

__global__ __launch_bounds__(256) void k_integ3(const float* __restrict__ carry,
                                                float* __restrict__ out) {
    __shared__ float dec[64];
    if (threadIdx.x == 0) {
        float d = 1.f;
        for (int i = 0; i < 64; ++i) { d *= 0.9f; dec[i] = d; }
    }
    __syncthreads();
    size_t id = (size_t)blockIdx.x * 256 + threadIdx.x;   // B*T*C exactly
    int c = (int)(id % CC);
    size_t bt = id / CC;
    int t = (int)(bt % TT);
    int b = (int)(bt / TT);
    int chunk = t >> 6, tl = t & 63;
    out[id] += dec[tl] * carry[((size_t)b * 16 + chunk) * CC + c];
}

// -----------------------------------------------------------------------------
extern "C" void kernel_launch(void* const* d_in, const int* in_sizes, int n_in,
                              void* d_out, int out_size, void* d_ws, size_t ws_size,
                              hipStream_t stream) {
    const float* x  = (const float*)d_in[0];
    const float* Wh = (const float*)d_in[1];
    const float* Wo = (const float*)d_in[2];

    char* p = (char*)d_ws;
    u64* me = (u64*)p;                        p += (size_t)BB * TT * 4 * 8;    // 16 MB
    u64* mh = (u64*)p;                        p += (size_t)BB * TT * 16 * 8;   // 64 MB
    unsigned short* Wt = (unsigned short*)p;  p += (size_t)HH * 512 * 2;       // 1 MB
    float* I = (float*)p;                     p += (size_t)BB * TT * CC * 4;   // 20 MB
    unsigned short* Wqo = (unsigned short*)p; p += (size_t)16 * 2048 * 2;      // 64 KB
    // vend/carry overlay the (dead after gemm) Wt region: 2 x 320 KB < 1 MB
    float* vend  = (float*)Wt;
    float* carry = (float*)(Wt + 512 * 512);  // +512 KB into Wt region

    hipLaunchKernelGGL(k_enc, dim3(BB), dim3(128), 0, stream, x, me);
    hipLaunchKernelGGL(k_quant, dim3(2048), dim3(256), 0, stream, Wh, Wt);
    hipLaunchKernelGGL(k_quant_o, dim3(128), dim3(256), 0, stream, Wo, Wqo);
    hipLaunchKernelGGL(k_gemm_scan, dim3(128, 8), dim3(256), 0, stream, me, Wt, mh);
    hipLaunchKernelGGL(k_outcur_mfma, dim3(2048), dim3(256), 0, stream, mh, Wqo, I);
    hipLaunchKernelGGL(k_integ1, dim3(BB), dim3(192), 0, stream, I, (float*)d_out, vend);
    hipLaunchKernelGGL(k_integ2, dim3(20), dim3(256), 0, stream, vend, carry);
    hipLaunchKernelGGL(k_integ3, dim3(20480), dim3(256), 0, stream, carry, (float*)d_out);
}